// Round 1
// 391.600 us; speedup vs baseline: 1.0052x; 1.0052x over previous
//
#include <hip/hip_runtime.h>
#include <math.h>

#define BB 8
#define CC 1024
#define LL 4096
#define NPB (CC*LL)          // 4194304 elements per batch
#define LT 32                // l-tile per fused block

// ws layout:
//   [0,128)    double sums[16]      (S1,S2 per batch)
//   [128,136)  double lossAcc

// grid (256, 8) x 256 threads. Each thread: 16 float4 of xt, strided, unroll 4.
__global__ void k_batch_sums(const float* __restrict__ xt, double* __restrict__ sums) {
    int b = blockIdx.y;
    const float4* p = (const float4*)(xt + (size_t)b * NPB);
    int t = blockIdx.x * blockDim.x + threadIdx.x;      // [0, 65536)
    double s1 = 0.0, s2 = 0.0;
    #pragma unroll
    for (int j4 = 0; j4 < 4; ++j4) {
        float4 v[4];
        #pragma unroll
        for (int k = 0; k < 4; ++k) v[k] = p[(size_t)(j4 * 4 + k) * 65536 + t];
        #pragma unroll
        for (int k = 0; k < 4; ++k) {
            float q1 = (v[k].x + v[k].y) + (v[k].z + v[k].w);
            float q2 = (v[k].x * v[k].x + v[k].y * v[k].y)
                     + (v[k].z * v[k].z + v[k].w * v[k].w);
            s1 += (double)q1;
            s2 += (double)q2;
        }
    }
    for (int off = 32; off; off >>= 1) {
        s1 += __shfl_down(s1, off, 64);
        s2 += __shfl_down(s2, off, 64);
    }
    __shared__ double ls1[4], ls2[4];
    int lane = threadIdx.x & 63, w = threadIdx.x >> 6;
    if (lane == 0) { ls1[w] = s1; ls2[w] = s2; }
    __syncthreads();
    if (threadIdx.x == 0) {
        atomicAdd(&sums[2 * b],     ls1[0] + ls1[1] + ls1[2] + ls1[3]);
        atomicAdd(&sums[2 * b + 1], ls2[0] + ls2[1] + ls2[2] + ls2[3]);
    }
}

// Fused colstats + entropy. grid (LL/LT=128, 8) x 1024 threads (16 waves).
// Block owns (b, l in [L0,L0+32)) for ALL C=1024 channels.
// Thread: q = tid&7 -> l-quad l = L0+q*4..+3 ; g = tid>>3 -> c = g + 128*i, i<8.
// Per c, 8 consecutive lanes x float4 = 128 B contiguous (full lines).
// Pass 1: load xs,xt once; keep exp(xs) and y=max(xt,mg) in registers (64 VGPR),
// accumulate per-l column sums; reduce via shfl_xor(8,16,32) + LDS across 16 waves.
// Pass 2: entropy from registers, write out, accumulate loss.
__global__ __launch_bounds__(1024)
void k_fused(const float* __restrict__ xs, const float* __restrict__ xt,
             const double* __restrict__ sums,
             float* __restrict__ out1, double* __restrict__ lossAcc) {
    int tid = threadIdx.x;
    int b = blockIdx.y;
    int L0 = blockIdx.x * LT;
    int q = tid & 7;
    int g = tid >> 3;
    int lane = tid & 63, w = tid >> 6;

    __shared__ float s_mg;
    __shared__ __align__(16) float s_red[2][16][8][4];   // [arr][wave][q][k]
    __shared__ __align__(16) float s_sinv[8][4];
    __shared__ __align__(16) float s_blog[8][4];
    __shared__ float wacc[16];

    if (tid == 0) {
        // inline margin from batch sums (double precision, ddof=1)
        double n = (double)NPB;
        double s1 = sums[2 * b], s2 = sums[2 * b + 1];
        double mean = s1 / n;
        double var = (s2 - s1 * s1 / n) / (n - 1.0);
        double sd = sqrt(var);
        double z = -mean / sd;
        double cdf = 0.5 * (1.0 + erf(z / 1.4142135623730951));
        double safe = fmax(cdf, 1e-30);
        double r = mean / sd;
        double ma = -sd * exp(-r * r * 0.5) / 2.5066282746310002 / safe + mean;
        s_mg = (float)((cdf > 0.001) ? ma : -3.0 * sd);
    }
    __syncthreads();
    float mg = s_mg;

    const float* ps = xs + (size_t)b * NPB + L0 + q * 4;
    const float* pt = xt + (size_t)b * NPB + L0 + q * 4;

    float4 es[8], yv[8];
    float ss[4] = {0, 0, 0, 0}, sy[4] = {0, 0, 0, 0};
    #pragma unroll
    for (int i = 0; i < 8; ++i) {
        size_t off = (size_t)(g + 128 * i) * LL;
        float4 s4 = *(const float4*)(ps + off);
        float4 t4 = *(const float4*)(pt + off);
        float4 e, y;
        e.x = __expf(s4.x); e.y = __expf(s4.y); e.z = __expf(s4.z); e.w = __expf(s4.w);
        y.x = fmaxf(t4.x, mg); y.y = fmaxf(t4.y, mg);
        y.z = fmaxf(t4.z, mg); y.w = fmaxf(t4.w, mg);
        es[i] = e; yv[i] = y;
        ss[0] += e.x; ss[1] += e.y; ss[2] += e.z; ss[3] += e.w;
        sy[0] += __expf(y.x); sy[1] += __expf(y.y);
        sy[2] += __expf(y.z); sy[3] += __expf(y.w);
    }
    // reduce across the 8 lanes-per-q inside each wave
    #pragma unroll
    for (int off = 8; off < 64; off <<= 1) {
        #pragma unroll
        for (int k = 0; k < 4; ++k) {
            ss[k] += __shfl_xor(ss[k], off, 64);
            sy[k] += __shfl_xor(sy[k], off, 64);
        }
    }
    if (lane < 8) {
        #pragma unroll
        for (int k = 0; k < 4; ++k) {
            s_red[0][w][lane][k] = ss[k];
            s_red[1][w][lane][k] = sy[k];
        }
    }
    __syncthreads();
    if (tid < 64) {
        int a  = tid >> 5;          // 0 = ss, 1 = sy
        int qq = (tid >> 2) & 7;
        int k  = tid & 3;
        float t = 0.f;
        #pragma unroll
        for (int ww = 0; ww < 16; ++ww) t += s_red[a][ww][qq][k];
        if (a == 0) s_sinv[qq][k] = 1.0f / t;      // 1/sum(exp(xs))
        else        s_blog[qq][k] = __logf(t);     // log(sum(exp(y)))
    }
    __syncthreads();
    float4 sinv = *(const float4*)&s_sinv[q][0];
    float4 blog = *(const float4*)&s_blog[q][0];

    float* po = out1 + (size_t)b * NPB + L0 + q * 4;
    float acc = 0.f;
    #pragma unroll
    for (int i = 0; i < 8; ++i) {
        size_t off = (size_t)(g + 128 * i) * LL;
        float4 e;
        e.x = es[i].x * sinv.x * (yv[i].x - blog.x);
        e.y = es[i].y * sinv.y * (yv[i].y - blog.y);
        e.z = es[i].z * sinv.z * (yv[i].z - blog.z);
        e.w = es[i].w * sinv.w * (yv[i].w - blog.w);
        *(float4*)(po + off) = e;   // 4B-aligned; float4 store is HW-legal
        acc += (e.x + e.y) + (e.z + e.w);
    }
    for (int off = 32; off; off >>= 1) acc += __shfl_down(acc, off, 64);
    if (lane == 0) wacc[w] = acc;
    __syncthreads();
    if (tid == 0) {
        double t = 0.0;
        #pragma unroll
        for (int ww = 0; ww < 16; ++ww) t += (double)wacc[ww];
        atomicAdd(lossAcc, t);
    }
}

__global__ void k_finalize(const double* __restrict__ lossAcc, float* __restrict__ out) {
    if (threadIdx.x == 0) out[0] = (float)(-lossAcc[0] / (double)(BB * LL));
}

extern "C" void kernel_launch(void* const* d_in, const int* in_sizes, int n_in,
                              void* d_out, int out_size, void* d_ws, size_t ws_size,
                              hipStream_t stream) {
    const float* x_ts = (const float*)d_in[2];  // source xs
    const float* x_st = (const float*)d_in[3];  // target xt
    float* out = (float*)d_out;

    double* sums    = (double*)d_ws;
    double* lossAcc = (double*)((char*)d_ws + 128);

    hipMemsetAsync(d_ws, 0, 256, stream);

    k_batch_sums<<<dim3(256, BB), 256, 0, stream>>>(x_st, sums);
    k_fused<<<dim3(LL / LT, BB), 1024, 0, stream>>>(x_ts, x_st, sums, out + 1, lossAcc);
    k_finalize<<<1, 64, 0, stream>>>(lossAcc, out);
}